// Round 1
// baseline (295.576 us; speedup 1.0000x reference)
//
#include <hip/hip_runtime.h>

// LookupLanguageModel: n-gram backoff LM over a CSR-flattened trie.
// One thread per (b, v). Per-batch context chain precomputed in lm_prep.

#define MAXN 8

struct PerB {
  int   ctx[MAXN];   // context tokens ctx[0..N-2] (after sos shift mapping)
  float bo[MAXN];    // cur_backoffs for step n (valid for n=1..N-2)
  float b1;          // initial last_backoffs = logbs[ctx[N-2]]
  int   hp;          // hidx + pad
};

// Find child of node q with token id t within window [start, start+S).
// ids within a node's child window are sorted ascending, unique, >= 0
// (guaranteed by the trie builder). Hence ids[start+j] >= j, which makes the
// single adaptive probe at j = min(t, n-1) decisive in the common case:
//   probe == t -> found; probe < t (only possible at j == n-1) -> not found;
//   probe > t -> fall back to binary search in [0, j).
__device__ __forceinline__ bool find_child(const int* __restrict__ offsets,
                                           const int* __restrict__ ids,
                                           int q, int t, int U, int P, int S,
                                           int* pos_out) {
  int start = offsets[q] + q;
  int end   = offsets[q + 1] + q + 1;
  int n = end - start;
  if (n > S) n = S;
  if (n <= 0) return false;
  int j = (t < n - 1) ? t : (n - 1);
  if (j < 0) j = 0;
  int x = ids[min(start + j, P - 1) - U];
  if (x == t) { *pos_out = start + j; return true; }
  if (x < t) return false;  // j == n-1 and max id < t
  // binary search in [0, j)
  int lo = 0, hi = j - 1;
  while (lo < hi) {
    int mid = (lo + hi) >> 1;
    int xm = ids[min(start + mid, P - 1) - U];
    if (xm < t) lo = mid + 1; else hi = mid;
  }
  if (lo < j) {
    int xm = ids[min(start + lo, P - 1) - U];
    if (xm == t) { *pos_out = start + lo; return true; }
  }
  return false;
}

__global__ void lm_prep(const int* __restrict__ hist, const int* __restrict__ hidx,
                        const int* __restrict__ offsets, const int* __restrict__ ids,
                        const float* __restrict__ logbs,
                        const int* __restrict__ sos_p, const int* __restrict__ N_p,
                        const int* __restrict__ S_p,
                        PerB* __restrict__ pb, int V, int B, int L, int O, int P) {
  int b = blockIdx.x * blockDim.x + threadIdx.x;
  if (b >= B) return;
  int sos = *sos_p, N = *N_p, S = *S_p;
  if (N <= 1) return;
  int shift = (0 <= sos && sos < V) ? 0 : 1;
  int U = V + shift + 1 % N;
  int pad = N - 1;
  int hp = hidx[b] + pad;
  PerB o;
  o.hp = hp;
  for (int k = 0; k < N - 1; ++k) {
    int r = hp - (N - 1) + k;  // index into padded history
    int tok = (r < pad) ? sos : hist[(r - pad) * B + b];
    if (shift && tok == sos) tok = V;
    o.ctx[k] = tok;
  }
  o.b1 = logbs[o.ctx[N - 2]];
  // context chain: desc starts at last context token; backoff collected per n
  int desc = o.ctx[N - 2];
  bool found = true;
  for (int n = 1; n <= N - 2; ++n) {
    int t = o.ctx[(N - 1) - min(n + 1, N - 1)];
    if (found) {
      int pos;
      found = find_child(offsets, ids, desc, t, U, P, S, &pos);
      if (found) desc = pos;
    }
    o.bo[n] = found ? logbs[min(desc, O - 1)] : 0.0f;
  }
  pb[b] = o;
}

__device__ __forceinline__ float score_v(const int* __restrict__ offsets,
                                         const int* __restrict__ ids,
                                         const float* __restrict__ logps,
                                         const PerB* __restrict__ pbb,
                                         int v, float lp0,
                                         int N, int U, int O, int P, int S) {
  float last_lp = lp0;
  float last_bo = pbb->b1;
  int hp = pbb->hp;
  int desc = v;
  bool found = true;
  float cur_lp = lp0;  // logps[desc], cached (desc only changes when found)
#pragma unroll
  for (int n = 1; n <= N - 1; ++n) {
    int t = pbb->ctx[(N - 1) - n];
    if (found) {
      int pos;
      found = find_child(offsets, ids, desc, t, U, P, S, &pos);
      if (found) { desc = pos; cur_lp = logps[desc]; }
    }
    float cur_bo = (n == N - 1) ? 0.0f : pbb->bo[n];
    bool clobber = isfinite(cur_lp) && found;
    float newlp = clobber ? cur_lp : (last_lp + cur_bo + last_bo);
    last_bo = clobber ? cur_bo : 0.0f;
    if (hp >= n) last_lp = newlp;
  }
  return last_lp;
}

__global__ void __launch_bounds__(256)
lm_main(const int* __restrict__ offsets, const int* __restrict__ ids,
        const float* __restrict__ logps, const float* __restrict__ logbs,
        const int* __restrict__ sos_p, const int* __restrict__ N_p,
        const int* __restrict__ S_p,
        const PerB* __restrict__ pb, float* __restrict__ out,
        int V, int B, int O, int P) {
  int v = blockIdx.x * blockDim.x + threadIdx.x;
  int b = blockIdx.y;
  if (v >= V) return;
  int N = *N_p;
  float lp0 = logps[v];
  size_t oi = (size_t)b * (size_t)V + (size_t)v;
  if (N <= 1) { out[oi] = lp0; return; }
  int S = *S_p;
  int sos = *sos_p;
  int shift = (0 <= sos && sos < V) ? 0 : 1;
  int U = V + shift + 1 % N;
  const PerB* pbb = pb + b;
  float r;
  if (N == 3) {
    r = score_v(offsets, ids, logps, pbb, v, lp0, 3, U, O, P, S);
  } else {
    r = score_v(offsets, ids, logps, pbb, v, lp0, N, U, O, P, S);
  }
  out[oi] = r;
}

extern "C" void kernel_launch(void* const* d_in, const int* in_sizes, int n_in,
                              void* d_out, int out_size, void* d_ws, size_t ws_size,
                              hipStream_t stream) {
  const int*   hist    = (const int*)d_in[0];
  const int*   hidx    = (const int*)d_in[1];
  const int*   offsets = (const int*)d_in[2];
  const int*   ids     = (const int*)d_in[3];
  const float* logps   = (const float*)d_in[4];
  const float* logbs   = (const float*)d_in[5];
  const int*   sos_p   = (const int*)d_in[6];
  const int*   N_p     = (const int*)d_in[8];
  const int*   S_p     = (const int*)d_in[10];

  int B = in_sizes[1];
  int L = in_sizes[0] / B;
  int O = in_sizes[2];
  int P = in_sizes[4];
  int V = out_size / B;
  float* out = (float*)d_out;
  PerB* pb = (PerB*)d_ws;

  lm_prep<<<dim3((B + 63) / 64), dim3(64), 0, stream>>>(
      hist, hidx, offsets, ids, logbs, sos_p, N_p, S_p, pb, V, B, L, O, P);

  dim3 grid((V + 255) / 256, B);
  lm_main<<<grid, dim3(256), 0, stream>>>(
      offsets, ids, logps, logbs, sos_p, N_p, S_p, pb, out, V, B, O, P);
}

// Round 2
// 292.432 us; speedup vs baseline: 1.0108x; 1.0108x over previous
//
#include <hip/hip_runtime.h>

// LookupLanguageModel: n-gram backoff LM over a CSR-flattened trie.
// One thread per (b, v). Per-batch context chain precomputed in lm_prep.
// lm_main (N==3 path) uses speculative parallel issue: at each trie level the
// candidate child position j = min(t, nchild-1) is computable from the node's
// offsets alone (ids sorted, unique, >=0 => ids[start+j] >= j), so the id
// probe, the child's logps, and the child's own offsets window are issued
// concurrently -> dependent-load chain of 3 levels instead of 5.

#define MAXN 8

struct PerB {
  int   ctx[MAXN];   // context tokens ctx[0..N-2] (after sos shift mapping)
  float bo[MAXN];    // cur_backoffs for step n (valid for n=1..N-2)
  float b1;          // initial last_backoffs = logbs[ctx[N-2]]
  int   hp;          // hidx + pad
};

__device__ __forceinline__ bool find_child(const int* __restrict__ offsets,
                                           const int* __restrict__ ids,
                                           int q, int t, int U, int P, int S,
                                           int* pos_out) {
  int start = offsets[q] + q;
  int end   = offsets[q + 1] + q + 1;
  int n = end - start;
  if (n > S) n = S;
  if (n <= 0) return false;
  int j = (t < n - 1) ? t : (n - 1);
  if (j < 0) j = 0;
  int x = ids[min(start + j, P - 1) - U];
  if (x == t) { *pos_out = start + j; return true; }
  if (x < t) return false;  // j == n-1 and max id < t
  int lo = 0, hi = j - 1;
  while (lo < hi) {
    int mid = (lo + hi) >> 1;
    int xm = ids[min(start + mid, P - 1) - U];
    if (xm < t) lo = mid + 1; else hi = mid;
  }
  if (lo < j) {
    int xm = ids[min(start + lo, P - 1) - U];
    if (xm == t) { *pos_out = start + lo; return true; }
  }
  return false;
}

__global__ void lm_prep(const int* __restrict__ hist, const int* __restrict__ hidx,
                        const int* __restrict__ offsets, const int* __restrict__ ids,
                        const float* __restrict__ logbs,
                        const int* __restrict__ sos_p, const int* __restrict__ N_p,
                        const int* __restrict__ S_p,
                        PerB* __restrict__ pb, int V, int B, int L, int O, int P) {
  int b = blockIdx.x * blockDim.x + threadIdx.x;
  if (b >= B) return;
  int sos = *sos_p, N = *N_p, S = *S_p;
  if (N <= 1) return;
  int shift = (0 <= sos && sos < V) ? 0 : 1;
  int U = V + shift + 1 % N;
  int pad = N - 1;
  int hp = hidx[b] + pad;
  PerB o;
  o.hp = hp;
  for (int k = 0; k < N - 1; ++k) {
    int r = hp - (N - 1) + k;
    int tok = (r < pad) ? sos : hist[(r - pad) * B + b];
    if (shift && tok == sos) tok = V;
    o.ctx[k] = tok;
  }
  o.b1 = logbs[o.ctx[N - 2]];
  int desc = o.ctx[N - 2];
  bool found = true;
  for (int n = 1; n <= N - 2; ++n) {
    int t = o.ctx[(N - 1) - min(n + 1, N - 1)];
    if (found) {
      int pos;
      found = find_child(offsets, ids, desc, t, U, P, S, &pos);
      if (found) desc = pos;
    }
    o.bo[n] = found ? logbs[min(desc, O - 1)] : 0.0f;
  }
  pb[b] = o;
}

// Generic (N != 3) fallback, sequential levels.
__device__ __forceinline__ float score_v(const int* __restrict__ offsets,
                                         const int* __restrict__ ids,
                                         const float* __restrict__ logps,
                                         const PerB* __restrict__ pbb,
                                         int v, float lp0,
                                         int N, int U, int O, int P, int S) {
  float last_lp = lp0;
  float last_bo = pbb->b1;
  int hp = pbb->hp;
  int desc = v;
  bool found = true;
  float cur_lp = lp0;
  for (int n = 1; n <= N - 1; ++n) {
    int t = pbb->ctx[(N - 1) - n];
    if (found) {
      int pos;
      found = find_child(offsets, ids, desc, t, U, P, S, &pos);
      if (found) { desc = pos; cur_lp = logps[desc]; }
    }
    float cur_bo = (n == N - 1) ? 0.0f : pbb->bo[n];
    bool clobber = isfinite(cur_lp) && found;
    float newlp = clobber ? cur_lp : (last_lp + cur_bo + last_bo);
    last_bo = clobber ? cur_bo : 0.0f;
    if (hp >= n) last_lp = newlp;
  }
  return last_lp;
}

__global__ void __launch_bounds__(256)
lm_main(const int* __restrict__ offsets, const int* __restrict__ ids,
        const float* __restrict__ logps,
        const int* __restrict__ sos_p, const int* __restrict__ N_p,
        const int* __restrict__ S_p,
        const PerB* __restrict__ pb, float* __restrict__ out,
        int V, int B, int O, int P) {
  int v = blockIdx.x * blockDim.x + threadIdx.x;
  int b = blockIdx.y;
  if (v >= V) return;
  int N = *N_p;
  float lp0 = logps[v];
  size_t oi = (size_t)b * (size_t)V + (size_t)v;
  if (N <= 1) { out[oi] = lp0; return; }
  int S = *S_p;
  int sos = *sos_p;
  int shift = (0 <= sos && sos < V) ? 0 : 1;
  int U = V + shift + 1 % N;
  const PerB* pbb = pb + b;

  if (N != 3) {
    out[oi] = score_v(offsets, ids, logps, pbb, v, lp0, N, U, O, P, S);
    return;
  }

  // ---- N == 3 speculative path ----
  int   t1  = pbb->ctx[1];   // matched at level n=1 (most recent token)
  int   t0  = pbb->ctx[0];   // matched at level n=2
  float bo1 = pbb->bo[1];    // context-chain backoff for n=1
  float lb0 = pbb->b1;       // initial last_backoffs
  int   hp  = pbb->hp;

  float last_lp = lp0;
  float last_bo = lb0;

  // Level 1: children of unigram v
  int ov  = offsets[v];
  int ov1 = offsets[v + 1];
  int start1 = ov + v;
  int n1 = ov1 + 1 - ov;
  if (n1 > S) n1 = S;

  bool found = false;
  int   q1 = v;
  float lp1 = 0.0f;
  int   ob = 0, ob1 = 0;

  if (n1 > 0) {
    int j1 = (t1 < n1 - 1) ? t1 : (n1 - 1);
    if (j1 < 0) j1 = 0;
    int c1  = start1 + j1;
    int c1c = min(c1, P - 1);
    // parallel issue: probe + speculative child logps + speculative child offsets
    int   x1 = ids[c1c - U];
    float sp = logps[c1c];
    int   qc = min(c1, O - 2);
    int   so = offsets[qc];
    int   so1 = offsets[qc + 1];
    if (x1 == t1) {
      found = true; q1 = c1; lp1 = sp; ob = so; ob1 = so1;
    } else if (x1 > t1) {
      // rare slow path: binary search [0, j1)
      int lo = 0, hi = j1 - 1;
      while (lo < hi) {
        int mid = (lo + hi) >> 1;
        int xm = ids[min(start1 + mid, P - 1) - U];
        if (xm < t1) lo = mid + 1; else hi = mid;
      }
      if (lo < j1 && ids[min(start1 + lo, P - 1) - U] == t1) {
        found = true; q1 = start1 + lo;
        int cc = min(q1, P - 1);
        lp1 = logps[cc];
        int qc2 = min(q1, O - 2);
        ob = offsets[qc2]; ob1 = offsets[qc2 + 1];
      }
    }
  }

  // n = 1 update
  {
    float cur_lp = found ? lp1 : lp0;        // logps[desc]
    bool clobber = isfinite(cur_lp) && found;
    float newlp = clobber ? cur_lp : (last_lp + bo1 + last_bo);
    last_bo = clobber ? bo1 : 0.0f;
    if (hp >= 1) last_lp = newlp;
  }

  // Level 2 (trigram): only if level-1 found; wave-uniform branch (t1 per-b)
  if (found) {
    int start2 = ob + q1;
    int n2 = ob1 + 1 - ob;
    if (n2 > S) n2 = S;
    bool found2 = false;
    float lp2 = 0.0f;
    if (n2 > 0) {
      int j2 = (t0 < n2 - 1) ? t0 : (n2 - 1);
      if (j2 < 0) j2 = 0;
      int c2  = start2 + j2;
      int c2c = min(c2, P - 1);
      int   x2 = ids[c2c - U];
      float sp2 = logps[c2c];
      if (x2 == t0) {
        found2 = true; lp2 = sp2;
      } else if (x2 > t0) {
        int lo = 0, hi = j2 - 1;
        while (lo < hi) {
          int mid = (lo + hi) >> 1;
          int xm = ids[min(start2 + mid, P - 1) - U];
          if (xm < t0) lo = mid + 1; else hi = mid;
        }
        if (lo < j2 && ids[min(start2 + lo, P - 1) - U] == t0) {
          found2 = true; lp2 = logps[min(start2 + lo, P - 1)];
        }
      }
    }
    float nl2;
    bool clobber2 = found2 && isfinite(lp2);
    nl2 = clobber2 ? lp2 : (last_lp + 0.0f + last_bo);
    if (hp >= 2) last_lp = nl2;
  } else {
    // found stays false: clobber false, cur_bo = 0 at n = N-1
    float nl2 = last_lp + last_bo;
    if (hp >= 2) last_lp = nl2;
  }

  out[oi] = last_lp;
}

extern "C" void kernel_launch(void* const* d_in, const int* in_sizes, int n_in,
                              void* d_out, int out_size, void* d_ws, size_t ws_size,
                              hipStream_t stream) {
  const int*   hist    = (const int*)d_in[0];
  const int*   hidx    = (const int*)d_in[1];
  const int*   offsets = (const int*)d_in[2];
  const int*   ids     = (const int*)d_in[3];
  const float* logps   = (const float*)d_in[4];
  const float* logbs   = (const float*)d_in[5];
  const int*   sos_p   = (const int*)d_in[6];
  const int*   N_p     = (const int*)d_in[8];
  const int*   S_p     = (const int*)d_in[10];

  int B = in_sizes[1];
  int L = in_sizes[0] / B;
  int O = in_sizes[2];
  int P = in_sizes[4];
  int V = out_size / B;
  float* out = (float*)d_out;
  PerB* pb = (PerB*)d_ws;

  lm_prep<<<dim3((B + 63) / 64), dim3(64), 0, stream>>>(
      hist, hidx, offsets, ids, logbs, sos_p, N_p, S_p, pb, V, B, L, O, P);

  dim3 grid((V + 255) / 256, B);
  lm_main<<<grid, dim3(256), 0, stream>>>(
      offsets, ids, logps, sos_p, N_p, S_p, pb, out, V, B, O, P);
}

// Round 3
// 278.908 us; speedup vs baseline: 1.0598x; 1.0485x over previous
//
#include <hip/hip_runtime.h>
#include <math.h>

// LookupLanguageModel: n-gram backoff LM over a CSR-flattened trie.
// v-major restructure: one thread owns one vocabulary item v for a group of
// BG batches. The level-1 (bigram) child-id window and child-offsets window
// of node v are staged ONCE into LDS via vector loads and reused for all BG
// batches (previously re-fetched from HBM per batch -> ~260 MB of traffic).
// Only trigram probes/logps gathers (distinct 64B lines per (b,v)) stay
// global. Odd LDS strides (37/41) make the per-lane indexed reads
// bank-conflict-free.

#define MAXN 8
#define BG   16
#define WI   37   // LDS row stride for ids window (odd => conflict-free)
#define WO   41   // LDS row stride for offsets window (odd)

struct PerB {
  int   ctx[MAXN];   // context tokens ctx[0..N-2] (after sos shift mapping)
  float bo[MAXN];    // cur_backoffs for step n (valid for n=1..N-2)
  float b1;          // initial last_backoffs = logbs[ctx[N-2]]
  int   hp;          // hidx + pad
};

__device__ __forceinline__ bool find_child(const int* __restrict__ offsets,
                                           const int* __restrict__ ids,
                                           int q, int t, int U, int P, int S,
                                           int* pos_out) {
  int start = offsets[q] + q;
  int end   = offsets[q + 1] + q + 1;
  int n = end - start;
  if (n > S) n = S;
  if (n <= 0) return false;
  int j = (t < n - 1) ? t : (n - 1);
  if (j < 0) j = 0;
  int x = ids[min(start + j, P - 1) - U];
  if (x == t) { *pos_out = start + j; return true; }
  if (x < t) return false;  // sorted: max id in window < t
  int lo = 0, hi = j - 1;
  while (lo < hi) {
    int mid = (lo + hi) >> 1;
    int xm = ids[min(start + mid, P - 1) - U];
    if (xm < t) lo = mid + 1; else hi = mid;
  }
  if (lo < j) {
    int xm = ids[min(start + lo, P - 1) - U];
    if (xm == t) { *pos_out = start + lo; return true; }
  }
  return false;
}

__global__ void lm_prep(const int* __restrict__ hist, const int* __restrict__ hidx,
                        const int* __restrict__ offsets, const int* __restrict__ ids,
                        const float* __restrict__ logbs,
                        const int* __restrict__ sos_p, const int* __restrict__ N_p,
                        const int* __restrict__ S_p,
                        PerB* __restrict__ pb, int V, int B, int L, int O, int P) {
  int b = blockIdx.x * blockDim.x + threadIdx.x;
  if (b >= B) return;
  int sos = *sos_p, N = *N_p, S = *S_p;
  if (N <= 1) return;
  int shift = (0 <= sos && sos < V) ? 0 : 1;
  int U = V + shift + 1 % N;
  int pad = N - 1;
  int hp = hidx[b] + pad;
  PerB o;
  o.hp = hp;
  for (int k = 0; k < N - 1; ++k) {
    int r = hp - (N - 1) + k;
    int tok = (r < pad) ? sos : hist[(r - pad) * B + b];
    if (shift && tok == sos) tok = V;
    o.ctx[k] = tok;
  }
  o.b1 = logbs[o.ctx[N - 2]];
  int desc = o.ctx[N - 2];
  bool found = true;
  for (int n = 1; n <= N - 2; ++n) {
    int t = o.ctx[(N - 1) - min(n + 1, N - 1)];
    if (found) {
      int pos;
      found = find_child(offsets, ids, desc, t, U, P, S, &pos);
      if (found) desc = pos;
    }
    o.bo[n] = found ? logbs[min(desc, O - 1)] : 0.0f;
  }
  pb[b] = o;
}

// Generic fallback (any N, any S): sequential trie walk per (b, v).
__device__ __forceinline__ float score_v(const int* __restrict__ offsets,
                                         const int* __restrict__ ids,
                                         const float* __restrict__ logps,
                                         const PerB* __restrict__ pbb,
                                         int v, float lp0,
                                         int N, int U, int O, int P, int S) {
  float last_lp = lp0;
  float last_bo = pbb->b1;
  int hp = pbb->hp;
  int desc = v;
  bool found = true;
  float cur_lp = lp0;
  for (int n = 1; n <= N - 1; ++n) {
    int t = pbb->ctx[(N - 1) - n];
    if (found) {
      int pos;
      found = find_child(offsets, ids, desc, t, U, P, S, &pos);
      if (found) { desc = pos; cur_lp = logps[desc]; }
    }
    float cur_bo = (n == N - 1) ? 0.0f : pbb->bo[n];
    bool clobber = isfinite(cur_lp) && found;
    float newlp = clobber ? cur_lp : (last_lp + cur_bo + last_bo);
    last_bo = clobber ? cur_bo : 0.0f;
    if (hp >= n) last_lp = newlp;
  }
  return last_lp;
}

__global__ void __launch_bounds__(64)
lm_main2(const int* __restrict__ offsets, const int* __restrict__ ids,
         const float* __restrict__ logps,
         const int* __restrict__ sos_p, const int* __restrict__ N_p,
         const int* __restrict__ S_p,
         const PerB* __restrict__ pb, float* __restrict__ out,
         int V, int B, int O, int P) {
  __shared__ int   s_t1[BG], s_t0[BG], s_hp[BG];
  __shared__ float s_bo1[BG], s_b1[BG];
  __shared__ int   ids_w[64 * WI];
  __shared__ int   off_w[64 * WO];

  const int tid = threadIdx.x;
  const int v   = blockIdx.x * 64 + tid;
  const int b0  = blockIdx.y * BG;
  const int N = *N_p, S = *S_p, sos = *sos_p;
  const int Nc = (N > 0) ? N : 1;
  const int shift = (0 <= sos && sos < V) ? 0 : 1;
  const int U = V + shift + 1 % Nc;  // matches reference precedence

  const bool fast = (N == 3) && (S == 32);

  if (!fast) {
    if (v < V) {
      float lp0 = logps[v];
      if (N <= 1) {
        for (int i = 0; i < BG; ++i) {
          int b = b0 + i;
          if (b < B) out[(size_t)b * V + v] = lp0;
        }
      } else {
        for (int i = 0; i < BG; ++i) {
          int b = b0 + i;
          if (b < B)
            out[(size_t)b * V + v] = score_v(offsets, ids, logps, pb + b, v,
                                             lp0, N, U, O, P, S);
        }
      }
    }
    return;
  }

  // stage per-b state (block-uniform) into LDS
  if (tid < BG) {
    int b = b0 + tid;
    if (b < B) {
      const PerB* q = pb + b;
      s_t1[tid]  = q->ctx[1];
      s_t0[tid]  = q->ctx[0];
      s_bo1[tid] = q->bo[1];
      s_b1[tid]  = q->b1;
      s_hp[tid]  = q->hp;
    }
  }
  __syncthreads();
  if (v >= V) return;

  const int idsN = P - U;
  float lp0 = logps[v];
  int ov  = offsets[v];
  int ov1 = offsets[v + 1];
  int start1 = ov + v;
  int n1 = ov1 + 1 - ov;
  if (n1 > 32) n1 = 32;

  // stage this node's child-id window and child-offsets window into LDS
  int* myids = ids_w + tid * WI;
  int* myoff = off_w + tid * WO;
  int aidx0 = start1 - U;
  int sh_i = 0, sh_o = 0;
  bool vec_ok = (start1 >= 0) && (aidx0 >= 0) &&
                (((aidx0 & ~3) + 36) <= idsN) &&
                (((start1 & ~3) + 40) <= O);
  if (vec_ok) {
    int ab = aidx0 & ~3;
    sh_i = aidx0 - ab;
    const int4* ip = (const int4*)(ids + ab);
#pragma unroll
    for (int k = 0; k < 9; ++k) {
      int4 t = ip[k];
      myids[4 * k + 0] = t.x; myids[4 * k + 1] = t.y;
      myids[4 * k + 2] = t.z; myids[4 * k + 3] = t.w;
    }
    int ob = start1 & ~3;
    sh_o = start1 - ob;
    const int4* op = (const int4*)(offsets + ob);
#pragma unroll
    for (int k = 0; k < 10; ++k) {
      int4 t = op[k];
      myoff[4 * k + 0] = t.x; myoff[4 * k + 1] = t.y;
      myoff[4 * k + 2] = t.z; myoff[4 * k + 3] = t.w;
    }
  } else {
    for (int j = 0; j < 34; ++j) {
      int ii = min(start1 + j, P - 1) - U;
      ii = max(0, min(ii, idsN - 1));
      myids[j] = ids[ii];
      int oo = max(0, min(start1 + j, O - 1));
      myoff[j] = offsets[oo];
    }
  }
  // no barrier needed: each thread reads only its own LDS rows

#pragma unroll
  for (int i = 0; i < BG; ++i) {
    int b = b0 + i;
    if (b >= B) continue;
    int   t1 = s_t1[i], t0 = s_t0[i], hp = s_hp[i];
    float bo1 = s_bo1[i], last_bo = s_b1[i];
    float last_lp = lp0;

    // level 1 (bigram): resolve from LDS window
    bool found = false;
    int j1 = 0;
    if (n1 > 0) {
      int jj = (t1 < n1 - 1) ? t1 : (n1 - 1);
      if (jj < 0) jj = 0;
      int x = myids[sh_i + jj];
      if (x == t1) { found = true; j1 = jj; }
      else if (x > t1) {
        int lo = 0, hi = jj - 1;
        while (lo < hi) {
          int mid = (lo + hi) >> 1;
          if (myids[sh_i + mid] < t1) lo = mid + 1; else hi = mid;
        }
        if (lo < jj && myids[sh_i + lo] == t1) { found = true; j1 = lo; }
      }
    }
    int c1 = start1 + j1;
    float lp1 = found ? logps[min(c1, P - 1)] : lp0;

    // n = 1 update
    {
      bool clob = found && isfinite(lp1);
      float nl = clob ? lp1 : (last_lp + bo1 + last_bo);
      last_bo = clob ? bo1 : 0.0f;
      if (hp >= 1) last_lp = nl;
    }

    // level 2 (trigram): only if level-1 found (wave-uniform per b)
    if (found) {
      int o1 = myoff[sh_o + j1];
      int o2 = myoff[sh_o + j1 + 1];
      int start2 = o1 + c1;
      int n2 = o2 + 1 - o1;
      if (n2 > 32) n2 = 32;
      bool f2 = false;
      float lp2 = 0.0f;
      if (n2 > 0) {
        int jj = (t0 < n2 - 1) ? t0 : (n2 - 1);
        if (jj < 0) jj = 0;
        int c2 = start2 + jj;
        int cc = min(c2, P - 1);
        int ii = max(0, min(cc - U, idsN - 1));
        int   x2  = ids[ii];
        float sp2 = logps[cc];
        if (x2 == t0) { f2 = true; lp2 = sp2; }
        else if (x2 > t0) {
          int lo = 0, hi = jj - 1;
          while (lo < hi) {
            int mid = (lo + hi) >> 1;
            int im = max(0, min(min(start2 + mid, P - 1) - U, idsN - 1));
            if (ids[im] < t0) lo = mid + 1; else hi = mid;
          }
          if (lo < jj) {
            int il = max(0, min(min(start2 + lo, P - 1) - U, idsN - 1));
            if (ids[il] == t0) { f2 = true; lp2 = logps[min(start2 + lo, P - 1)]; }
          }
        }
      }
      bool clob2 = f2 && isfinite(lp2);
      float nl2 = clob2 ? lp2 : (last_lp + last_bo);
      if (hp >= 2) last_lp = nl2;
    } else {
      float nl2 = last_lp + last_bo;
      if (hp >= 2) last_lp = nl2;
    }

    out[(size_t)b * V + v] = last_lp;
  }
}

extern "C" void kernel_launch(void* const* d_in, const int* in_sizes, int n_in,
                              void* d_out, int out_size, void* d_ws, size_t ws_size,
                              hipStream_t stream) {
  const int*   hist    = (const int*)d_in[0];
  const int*   hidx    = (const int*)d_in[1];
  const int*   offsets = (const int*)d_in[2];
  const int*   ids     = (const int*)d_in[3];
  const float* logps   = (const float*)d_in[4];
  const float* logbs   = (const float*)d_in[5];
  const int*   sos_p   = (const int*)d_in[6];
  const int*   N_p     = (const int*)d_in[8];
  const int*   S_p     = (const int*)d_in[10];

  int B = in_sizes[1];
  int L = in_sizes[0] / B;
  int O = in_sizes[2];
  int P = in_sizes[4];
  int V = out_size / B;
  float* out = (float*)d_out;
  PerB* pb = (PerB*)d_ws;

  lm_prep<<<dim3((B + 63) / 64), dim3(64), 0, stream>>>(
      hist, hidx, offsets, ids, logbs, sos_p, N_p, S_p, pb, V, B, L, O, P);

  dim3 grid((V + 63) / 64, (B + BG - 1) / BG);
  lm_main2<<<grid, dim3(64), 0, stream>>>(
      offsets, ids, logps, sos_p, N_p, S_p, pb, out, V, B, O, P);
}